// Round 6
// baseline (403.528 us; speedup 1.0000x reference)
//
#include <hip/hip_runtime.h>
#include <math.h>

#define RANK 64
#define D_DIM 320          // ENT_COMPS * RANK
#define K_DIM 640          // 2 * D_DIM
#define N_ENT 80000
#define B_Q 2000
#define M_PAD 2048         // B_Q padded to multiple of 256
#define NBLK_N 313         // ceil(80000/256)
#define NT 10              // K_DIM / 64
#define SCALE_F 0.125f     // 1/sqrt(64)
#define EPS_F 1e-9f

// d_out layout (floats)
#define OFF_SCORES 0ull
#define OFF_REG0 160000000ull
#define OFF_REG1 160640000ull
#define OFF_REG2 161280000ull
#define OFF_REG3 161920000ull
#define OFF_REG4 162048000ull

typedef __attribute__((ext_vector_type(8))) short short8v;   // 8 bf16 (4 VGPRs)
typedef __attribute__((ext_vector_type(4))) float floatx4;

typedef __attribute__((address_space(1))) const unsigned int gu32;
typedef __attribute__((address_space(3))) unsigned int lu32;

#define VMCNT6() asm volatile("s_waitcnt vmcnt(6)" ::: "memory")
#define VMCNT4() asm volatile("s_waitcnt vmcnt(4)" ::: "memory")
#define VMCNT0() asm volatile("s_waitcnt vmcnt(0)" ::: "memory")
#define LGKM0()  asm volatile("s_waitcnt lgkmcnt(0)" ::: "memory")

static __device__ __forceinline__ unsigned short f2bf(float f) {
    union { float f; unsigned int u; } a; a.f = f;
    unsigned int u = a.u;
    u += 0x7FFFu + ((u >> 16) & 1u);   // RNE (finite inputs only)
    return (unsigned short)(u >> 16);
}

// ---------------------------------------------------------------------------
// Prep: one 64-lane block per (padded) query row. Lane k handles rank k.
// ---------------------------------------------------------------------------
__global__ __launch_bounds__(64) void prep_kernel(
    const int* __restrict__ q,
    const float* __restrict__ ent,       // (80000, 640)
    const float* __restrict__ rrot_t,    // (500, 64, 4)
    const float* __restrict__ rboost_t,  // (500, 64, 4)
    const float* __restrict__ atten_t,   // (500, 320)
    const float* __restrict__ aux_t,     // (500, 2, 320)
    unsigned short* __restrict__ X,      // (2048, 640) bf16 workspace
    float* __restrict__ out)
{
    int b = blockIdx.x;
    int lane = threadIdx.x;
    unsigned short* Xrow = X + (size_t)b * K_DIM;

    if (b >= B_Q) {  // zero pad rows so MFMA tiles read clean zeros
        #pragma unroll
        for (int c = 0; c < 10; c++) Xrow[lane * 10 + c] = 0;
        return;
    }

    int h = q[3 * b + 0];
    int r = q[3 * b + 1];
    int t = q[3 * b + 2];

    const float* eh = ent + (size_t)h * K_DIM;
    const float* et = ent + (size_t)t * K_DIM;

    float4 rv = *(const float4*)(rrot_t + (size_t)r * 256 + lane * 4);
    float4 bv = *(const float4*)(rboost_t + (size_t)r * 256 + lane * 4);

    const float* xr = eh + lane * 5;
    float x0 = xr[0], x1 = xr[1], x2 = xr[2], x3 = xr[3], x4 = xr[4];

    float rr2 = rv.x * rv.x + rv.y * rv.y + rv.z * rv.z + rv.w * rv.w;
    float rb2 = bv.x * bv.x + bv.y * bv.y + bv.z * bv.z + bv.w * bv.w;

    // rotate
    float qinv = 1.0f / sqrtf(rr2 + EPS_F);
    float qw = rv.x * qinv, qx = rv.y * qinv, qy = rv.z * qinv, qz = rv.w * qinv;
    float pw = x1, px = x2, py = x3, pz = x4;
    float rot[5];
    rot[0] = x0;
    rot[1] = qw * pw - qx * px - qy * py - qz * pz;
    rot[2] = qw * px + qx * pw + qy * pz - qz * py;
    rot[3] = qw * py - qx * pz + qy * pw + qz * px;
    rot[4] = qw * pz + qx * py - qy * px + qz * pw;

    // boost
    float vn2 = fminf(fmaxf(rb2, 0.0f), 0.999f);
    float sq = sqrtf(1.0f - vn2);
    float gamma = 1.0f / sq;
    float gm1 = vn2 / (sq * (1.0f + sq));  // gamma-1 without cancellation
    float vs = bv.x * x1 + bv.y * x2 + bv.z * x3 + bv.w * x4;
    float boo[5];
    boo[0] = gamma * (x0 + vs);
    float coef = gamma * x0 + gm1 * vs / (vn2 + EPS_F);
    boo[1] = x1 + coef * bv.x;
    boo[2] = x2 + coef * bv.y;
    boo[3] = x3 + coef * bv.z;
    boo[4] = x4 + coef * bv.w;

    // attention
    const float* at = atten_t + (size_t)r * D_DIM + lane * 5;
    float w0 = at[0] * rot[0] + at[1] * rot[1] + at[2] * rot[2] + at[3] * rot[3] + at[4] * rot[4];
    float w1 = at[0] * boo[0] + at[1] * boo[1] + at[2] * boo[2] + at[3] * boo[3] + at[4] * boo[4];
    #pragma unroll
    for (int off = 32; off; off >>= 1) {
        w0 += __shfl_xor(w0, off);
        w1 += __shfl_xor(w1, off);
    }
    w0 *= SCALE_F;
    w1 *= SCALE_F;
    float mx = fmaxf(w0, w1);
    float e0 = expf(w0 - mx), e1 = expf(w1 - mx);
    float inv = 1.0f / (e0 + e1);
    float wt0 = e0 * inv, wt1 = e1 * inv;

    const float* a0p = aux_t + (size_t)r * 640 + lane * 5;
    const float* a1p = a0p + D_DIM;
    float xre[5] = {x0, x1, x2, x3, x4};

    #pragma unroll
    for (int c = 0; c < 5; c++) {
        int d = lane * 5 + c;
        float lhs = wt0 * rot[c] + wt1 * boo[c];
        float im = eh[D_DIM + d];
        float a0 = a0p[c], a1 = a1p[c];
        Xrow[d]         = f2bf(lhs * a0 - im * a1);
        Xrow[D_DIM + d] = f2bf(lhs * a1 + im * a0);
        out[OFF_REG0 + (size_t)b * D_DIM + d] = sqrtf(xre[c] * xre[c] + im * im);
        out[OFF_REG1 + (size_t)b * D_DIM + d] = sqrtf(a0 * a0 + a1 * a1);
        float tre = et[d], tim = et[D_DIM + d];
        out[OFF_REG2 + (size_t)b * D_DIM + d] = sqrtf(tre * tre + tim * tim) * (1.0f / 3.0f);
    }
    out[OFF_REG3 + (size_t)b * RANK + lane] = sqrtf(rr2);
    out[OFF_REG4 + (size_t)b * RANK + lane] = sqrtf(rb2);
}

// ---------------------------------------------------------------------------
// E fp32 -> bf16 conversion, vectorized.
// ---------------------------------------------------------------------------
__global__ __launch_bounds__(256) void convE_kernel(
    const float* __restrict__ Ef, unsigned short* __restrict__ Eb)
{
    const size_t n4 = (size_t)N_ENT * K_DIM / 4;
    size_t stride = (size_t)gridDim.x * blockDim.x;
    for (size_t v = (size_t)blockIdx.x * blockDim.x + threadIdx.x; v < n4; v += stride) {
        float4 f = ((const float4*)Ef)[v];
        ushort4 u;
        u.x = f2bf(f.x); u.y = f2bf(f.y); u.z = f2bf(f.z); u.w = f2bf(f.w);
        ((ushort4*)Eb)[v] = u;
    }
}

// ---------------------------------------------------------------------------
// 8-phase-schedule MFMA GEMM (T3+T4+T5+T2): 256x256 tile, BK=64, 8 waves.
// LDS layout (shorts): offset(bufOff, mat, kk) = bufOff + mat*16384 + kk*8192,
// bufOff in {0, 32768}. 128 KB total.
// R4/R5 BUG (fixed): stage lambda took a buffer INDEX and multiplied by 32768,
// but callers passed the OFFSET (0/32768) -> base = 32768*32768 -> OOB LDS
// writes silently dropped -> all prefetched tiles read uninit LDS -> NaN.
// Lambda now takes the offset directly.
// Half-tile stream per K-tile: [A_k0, B_k0, A_k1, B_k1]; stage of tile t+1's
// half-tile p issues at tile t phase p. Counted vmcnt W={6,4,6,4}; prologue
// drains fully (scheduler may reorder loads within one asm-barrier region);
// peeled last tile {4,0,0,0}.
// XOR swizzle cb^=(row>>1)&3 (pre-swizzled global source + swizzled ds_read,
// rule-21 involution) -> 2-way bank access (free).
// ---------------------------------------------------------------------------
__global__ __launch_bounds__(512, 1) void gemm256(
    const unsigned short* __restrict__ X,   // (2048, 640) bf16
    const unsigned short* __restrict__ Eb,  // (80000, 640) bf16
    float* __restrict__ C)
{
    __shared__ unsigned short lds[65536];   // 128 KB

    const int tid = threadIdx.x;
    const int lane = tid & 63;
    const int wid = tid >> 6;
    const int wm = wid >> 2;          // 0..1  (128-row half of M)
    const int wn = wid & 3;           // 0..3  (64-col quarter of N)

    // XCD-aware mapping: m-block == XCD id; each XCD sweeps all of N.
    int bid = blockIdx.x;
    const int m0 = (bid & 7) * 256;
    const int n0 = (bid >> 3) * 256;

    const int fr = lane & 15;
    const int kq = lane >> 4;                     // 0..3
    const int cbs8 = (kq ^ ((fr >> 1) & 3)) * 8;  // swizzled 16B slot (shorts)

    floatx4 acc[8][4];
    #pragma unroll
    for (int i = 0; i < 8; i++)
        #pragma unroll
        for (int j = 0; j < 4; j++) acc[i][j] = (floatx4)0.0f;

    // stage geometry: row = tid>>2 (+128 for l=1), cb = tid&3; LDS dest linear
    // (byte offset = 16*tid within block = wave base + lane*16 ✓); global
    // k-slot pre-swizzled cb ^ ((row>>1)&3).
    const int srow = tid >> 2;       // 0..127
    const int scb = tid & 3;

    auto stage_ht = [&](int bufOff, int kt, int h) {  // h: 0=A_k0 1=B_k0 2=A_k1 3=B_k1
        const int mat = h & 1, kk = h >> 1;
        const int base = bufOff + mat * 16384 + kk * 8192;   // bufOff IS the offset
        #pragma unroll
        for (int l = 0; l < 2; l++) {
            int row = srow + l * 128;
            int colg = kk * 32 + ((scb ^ ((row >> 1) & 3)) * 8);
            const unsigned short* gp;
            if (mat == 0) {
                gp = X + (size_t)(m0 + row) * K_DIM + kt * 64 + colg;
            } else {
                int grow = n0 + row;
                if (grow > N_ENT - 1) grow = N_ENT - 1;  // tail clamp (finite, never stored)
                gp = Eb + (size_t)grow * K_DIM + kt * 64 + colg;
            }
            __builtin_amdgcn_global_load_lds((gu32*)gp,
                (lu32*)&lds[base + row * 32 + scb * 8], 16, 0, 0);
        }
    };

// One phase: quadrant (KK = k-half, IH = i-half), all j, 16 MFMA.
#define PHASE(KK, IH, WAITM, PF)                                              \
    {                                                                         \
        const unsigned short* Ab_ = lds + bufo + (KK) * 8192;                 \
        const unsigned short* Bb_ = lds + bufo + 16384 + (KK) * 8192;         \
        short8v a_[4], b_[4];                                                 \
        _Pragma("unroll")                                                     \
        for (int i2 = 0; i2 < 4; i2++) {                                      \
            int row = wm * 128 + ((IH) * 4 + i2) * 16 + fr;                   \
            a_[i2] = *(const short8v*)&Ab_[row * 32 + cbs8];                  \
        }                                                                     \
        _Pragma("unroll")                                                     \
        for (int j = 0; j < 4; j++) {                                         \
            int row = wn * 64 + j * 16 + fr;                                  \
            b_[j] = *(const short8v*)&Bb_[row * 32 + cbs8];                   \
        }                                                                     \
        if (PF) stage_ht(nbo, t + 1, (KK) * 2 + (IH));                        \
        WAITM();                                                              \
        __builtin_amdgcn_s_barrier();                                         \
        LGKM0();                                                              \
        __builtin_amdgcn_sched_barrier(0);                                    \
        __builtin_amdgcn_s_setprio(1);                                        \
        _Pragma("unroll")                                                     \
        for (int i2 = 0; i2 < 4; i2++)                                        \
            _Pragma("unroll")                                                 \
            for (int j = 0; j < 4; j++)                                       \
                acc[(IH) * 4 + i2][j] = __builtin_amdgcn_mfma_f32_16x16x32_bf16( \
                    a_[i2], b_[j], acc[(IH) * 4 + i2][j], 0, 0, 0);           \
        __builtin_amdgcn_s_setprio(0);                                        \
        __builtin_amdgcn_s_barrier();                                        \
    }

    // Prologue: stage tile 0 (4 half-tiles, 8 loads in ONE region) -> drain
    // FULLY (intra-region load order is scheduler-defined; partial counts
    // are only sound at asm-barrier granularity).
    #pragma unroll
    for (int h = 0; h < 4; h++) stage_ht(0, 0, h);
    VMCNT0();
    __builtin_amdgcn_s_barrier();

    for (int t = 0; t < NT - 1; t++) {
        const int bufo = (t & 1) * 32768;
        const int nbo = bufo ^ 32768;
        PHASE(0, 0, VMCNT6, true)
        PHASE(0, 1, VMCNT4, true)
        PHASE(1, 0, VMCNT6, true)
        PHASE(1, 1, VMCNT4, true)
    }
    {   // peeled last tile (t = NT-1): no prefetch.
        // Entry outstanding = tile9's A_k1,B_k1 (4 loads); k0 regions were
        // drained at tile 8 PHASE(1,1) + barrier. VMCNT0 at (0,1) drains k1
        // before (1,0)'s ds_read issue point.
        const int t = NT - 1;
        const int bufo = (t & 1) * 32768;
        const int nbo = bufo ^ 32768;
        (void)nbo;
        PHASE(0, 0, VMCNT4, false)
        PHASE(0, 1, VMCNT0, false)
        PHASE(1, 0, VMCNT0, false)
        PHASE(1, 1, VMCNT0, false)
    }
#undef PHASE

    // Epilogue: C/D layout col=lane&15, row=(lane>>4)*4+reg (m89-verified).
    const int rb = kq * 4;
    #pragma unroll
    for (int i = 0; i < 8; i++) {
        #pragma unroll
        for (int j = 0; j < 4; j++) {
            int row = m0 + wm * 128 + i * 16 + rb;
            int col = n0 + wn * 64 + j * 16 + fr;
            if (col < N_ENT) {
                #pragma unroll
                for (int r = 0; r < 4; r++) {
                    if (row + r < B_Q)
                        C[(size_t)(row + r) * N_ENT + col] = acc[i][j][r];
                }
            }
        }
    }
}

// ---------------------------------------------------------------------------
// Fallback GEMM (R2-verified) for ws-too-small case.
// ---------------------------------------------------------------------------
__global__ __launch_bounds__(256) void gemm_mfma_fb(
    const unsigned short* __restrict__ X,
    const float* __restrict__ Ef,
    float* __restrict__ C)
{
    __shared__ unsigned short As[128 * 32];
    __shared__ unsigned short Bs[128 * 32];

    const int tid = threadIdx.x;
    const int lane = tid & 63;
    const int wave = tid >> 6;
    const int wm = wave >> 1, wn = wave & 1;
    const int m0 = blockIdx.x * 128;
    const int n0 = blockIdx.y * 128;

    floatx4 acc[4][4];
    #pragma unroll
    for (int i = 0; i < 4; i++)
        #pragma unroll
        for (int j = 0; j < 4; j++) acc[i][j] = (floatx4)0.0f;

    const int srow = tid >> 2;
    const int scol = (tid & 3) * 8;
    const int fr = lane & 15;
    const int kb = (lane >> 4) * 8;
    const int brow_f = tid >> 1;
    const int bcol_f = (tid & 1) * 16;

    for (int k0 = 0; k0 < K_DIM; k0 += 32) {
        __syncthreads();
        #pragma unroll
        for (int r = 0; r < 2; r++) {
            const unsigned short* gp = X + (size_t)(m0 + srow + r * 64) * K_DIM + k0 + scol;
            __builtin_amdgcn_global_load_lds((gu32*)gp, (lu32*)(As + (size_t)(r * 64 + srow) * 32 + scol), 16, 0, 0);
        }
        {
            const float* ep = Ef + (size_t)(n0 + brow_f) * K_DIM + k0 + bcol_f;
            float4 f0 = *(const float4*)(ep);
            float4 f1 = *(const float4*)(ep + 4);
            float4 f2 = *(const float4*)(ep + 8);
            float4 f3 = *(const float4*)(ep + 12);
            short8v p0, p1;
            p0[0] = (short)f2bf(f0.x); p0[1] = (short)f2bf(f0.y);
            p0[2] = (short)f2bf(f0.z); p0[3] = (short)f2bf(f0.w);
            p0[4] = (short)f2bf(f1.x); p0[5] = (short)f2bf(f1.y);
            p0[6] = (short)f2bf(f1.z); p0[7] = (short)f2bf(f1.w);
            p1[0] = (short)f2bf(f2.x); p1[1] = (short)f2bf(f2.y);
            p1[2] = (short)f2bf(f2.z); p1[3] = (short)f2bf(f2.w);
            p1[4] = (short)f2bf(f3.x); p1[5] = (short)f2bf(f3.y);
            p1[6] = (short)f2bf(f3.z); p1[7] = (short)f2bf(f3.w);
            *(short8v*)(Bs + (size_t)brow_f * 32 + bcol_f) = p0;
            *(short8v*)(Bs + (size_t)brow_f * 32 + bcol_f + 8) = p1;
        }
        __syncthreads();

        short8v a[4], b[4];
        #pragma unroll
        for (int i = 0; i < 4; i++)
            a[i] = *(const short8v*)(As + (size_t)(wm * 64 + i * 16 + fr) * 32 + kb);
        #pragma unroll
        for (int j = 0; j < 4; j++)
            b[j] = *(const short8v*)(Bs + (size_t)(wn * 64 + j * 16 + fr) * 32 + kb);

        #pragma unroll
        for (int i = 0; i < 4; i++)
            #pragma unroll
            for (int j = 0; j < 4; j++)
                acc[i][j] = __builtin_amdgcn_mfma_f32_16x16x32_bf16(a[i], b[j], acc[i][j], 0, 0, 0);
    }

    const int rbase = (lane >> 4) * 4;
    #pragma unroll
    for (int i = 0; i < 4; i++) {
        #pragma unroll
        for (int j = 0; j < 4; j++) {
            int row = m0 + wm * 64 + i * 16 + rbase;
            int col = n0 + wn * 64 + j * 16 + fr;
            #pragma unroll
            for (int r = 0; r < 4; r++) {
                if (row + r < B_Q)
                    C[(size_t)(row + r) * N_ENT + col] = acc[i][j][r];
            }
        }
    }
}

extern "C" void kernel_launch(void* const* d_in, const int* in_sizes, int n_in,
                              void* d_out, int out_size, void* d_ws, size_t ws_size,
                              hipStream_t stream) {
    const int* queries = (const int*)d_in[0];
    const float* ent = (const float*)d_in[1];
    const float* rrot = (const float*)d_in[2];
    const float* rboost = (const float*)d_in[3];
    const float* atten = (const float*)d_in[4];
    const float* aux = (const float*)d_in[5];
    float* out = (float*)d_out;

    unsigned short* X = (unsigned short*)d_ws;            // 2048*640*2 = 2.62 MB
    const size_t offE = (size_t)M_PAD * K_DIM * 2;
    const size_t needE = (size_t)N_ENT * K_DIM * 2;       // 102.4 MB
    unsigned short* Eb = (unsigned short*)((char*)d_ws + offE);
    bool pre = (ws_size >= offE + needE);

    prep_kernel<<<M_PAD, 64, 0, stream>>>(queries, ent, rrot, rboost, atten, aux, X, out);

    if (pre) {
        convE_kernel<<<2048, 256, 0, stream>>>(ent, Eb);
        gemm256<<<8 * NBLK_N, 512, 0, stream>>>(X, Eb, out + OFF_SCORES);
    } else {
        dim3 grid(M_PAD / 128, N_ENT / 128);
        gemm_mfma_fb<<<grid, 256, 0, stream>>>(X, ent, out + OFF_SCORES);
    }
}